// Round 5
// baseline (603.706 us; speedup 1.0000x reference)
//
#include <hip/hip_runtime.h>

#define NN 100000
#define EE 1250000
#define DD 64
#define HH 256
#define NC_OUT 40
#define ALPHA_C 0.05f
#define COEF 0.2375f /* (1-ALPHA)/K */
#define EPS_C 1e-5f
#define NBUCK 391   /* ceil(NN/256) */
#define EPB 8192    /* edges per bucket-histogram block */
#define GB1 1563    /* (NN+63)/64 gemm blocks */
#define NRED 16

typedef __attribute__((ext_vector_type(8))) short short8;
typedef __attribute__((ext_vector_type(4))) float f32x4;

static __device__ __forceinline__ float bf2f(unsigned int u) {
  union { float f; unsigned int i; } x; x.i = u << 16; return x.f;
}
static __device__ __forceinline__ unsigned short f2bf(float f) {
  unsigned int x = __float_as_uint(f);
  unsigned int r = (x + 0x7FFFu + ((x >> 16) & 1u)) >> 16;
  return (unsigned short)r;
}

// ---------------- graph preprocessing ----------------

__global__ void k_count(const int* __restrict__ dst, int* __restrict__ deg) {
  int e = blockIdx.x * 256 + threadIdx.x;
  if (e < EE) atomicAdd(&deg[dst[e]], 1);
}

__global__ void k_scan1(const int* __restrict__ deg, int* __restrict__ rp,
                        int* __restrict__ bsum) {
  __shared__ int ts[256];
  int t = threadIdx.x;
  int base = blockIdx.x * 2048 + t * 8;
  int v[8]; int s = 0;
#pragma unroll
  for (int l = 0; l < 8; l++) { int i = base + l; v[l] = (i < NN) ? deg[i] : 0; s += v[l]; }
  ts[t] = s; __syncthreads();
  for (int off = 1; off < 256; off <<= 1) {
    int x = (t >= off) ? ts[t - off] : 0;
    __syncthreads();
    ts[t] += x;
    __syncthreads();
  }
  int run = ts[t] - s;
#pragma unroll
  for (int l = 0; l < 8; l++) { int i = base + l; if (i < NN) rp[i] = run; run += v[l]; }
  if (t == 255) bsum[blockIdx.x] = ts[255];
}

__global__ void k_scan2(const int* __restrict__ bsum, int* __restrict__ boff, int nb) {
  __shared__ int ts[64];
  int t = threadIdx.x;
  int x = (t < nb) ? bsum[t] : 0;
  ts[t] = x; __syncthreads();
  for (int off = 1; off < 64; off <<= 1) {
    int y = (t >= off) ? ts[t - off] : 0;
    __syncthreads();
    ts[t] += y;
    __syncthreads();
  }
  boff[t] = ts[t] - x;
}

__global__ void k_scan3(int* __restrict__ rp, const int* __restrict__ boff,
                        const int* __restrict__ deg, float* __restrict__ norm,
                        int* __restrict__ bcur) {
  int i = blockIdx.x * 256 + threadIdx.x;
  if (i < NN) {
    int r = rp[i] + boff[i >> 11];
    rp[i] = r;
    if ((i & 255) == 0) bcur[i >> 8] = r;
    int d = deg[i]; if (d < 1) d = 1;
    norm[i] = rsqrtf((float)d);
    if (i == 0) rp[NN] = EE;
  }
}

// pass B: scatter edges into per-bucket regions as packed words (src | local<<24)
__global__ __launch_bounds__(256) void k_bucket(const int* __restrict__ src,
                                                const int* __restrict__ dst,
                                                int* __restrict__ bcur,
                                                unsigned int* __restrict__ pairbuf) {
  __shared__ int hist[NBUCK];
  __shared__ int gbase[NBUCK];
  __shared__ int lcur[NBUCK];
  int tid = threadIdx.x;
  int e0 = blockIdx.x * EPB;
  int e1 = e0 + EPB; if (e1 > EE) e1 = EE;
  for (int i = tid; i < NBUCK; i += 256) { hist[i] = 0; lcur[i] = 0; }
  __syncthreads();
  for (int e = e0 + tid; e < e1; e += 256) {
    int b = dst[e] >> 8;
    atomicAdd(&hist[b], 1);
  }
  __syncthreads();
  for (int b = tid; b < NBUCK; b += 256) {
    int h = hist[b];
    gbase[b] = h ? atomicAdd(&bcur[b], h) : 0;
  }
  __syncthreads();
  for (int e = e0 + tid; e < e1; e += 256) {
    int d = dst[e];
    int b = d >> 8;
    int r = atomicAdd(&lcur[b], 1);
    pairbuf[gbase[b] + r] = (unsigned int)src[e] | ((unsigned int)(d & 255) << 24);
  }
}

// pass C: one block per bucket; LDS cursors scatter into the bucket's srt region
__global__ __launch_bounds__(256) void k_local(const unsigned int* __restrict__ pairbuf,
                                               const int* __restrict__ rp,
                                               int* __restrict__ srt) {
  __shared__ int cur[256];
  int b = blockIdx.x;
  int node0 = b << 8;
  int t = threadIdx.x;
  int node = node0 + t;
  cur[t] = (node < NN) ? rp[node] : 0;
  int lo = rp[node0];
  int hi = (node0 + 256 <= NN) ? rp[node0 + 256] : EE;
  __syncthreads();
  for (int e = lo + t; e < hi; e += 256) {
    unsigned int w = pairbuf[e];
    int s = (int)(w & 0x1FFFFu);
    int l = (int)(w >> 24);
    int p = atomicAdd(&cur[l], 1);
    srt[p] = s;
  }
}

// ---------------- propagation (hs in bf16) ----------------

__global__ void k_init(const float4* __restrict__ feat4, const float* __restrict__ norm,
                       uint2* __restrict__ hs, float4* __restrict__ acc4) {
  int i = blockIdx.x * 256 + threadIdx.x;
  if (i < NN * 16) {
    float nv = norm[i >> 4];
    float4 f = feat4[i];
    uint2 o;
    o.x = (unsigned int)f2bf(f.x * nv) | ((unsigned int)f2bf(f.y * nv) << 16);
    o.y = (unsigned int)f2bf(f.z * nv) | ((unsigned int)f2bf(f.w * nv) << 16);
    hs[i] = o;
    acc4[i] = make_float4(0.f, 0.f, 0.f, 0.f);
  }
}

// one wave per node, lane = feature (D=64); hs bf16; index-batch software pipeline
__global__ void k_gather(const unsigned short* __restrict__ hin,
                         unsigned short* __restrict__ hout,
                         float* __restrict__ accum, const int* __restrict__ rp,
                         const int* __restrict__ srt, const float* __restrict__ norm) {
  int node = blockIdx.x * 4 + (threadIdx.x >> 6);
  int lane = threadIdx.x & 63;
  if (node >= NN) return;
  int beg = rp[node], end = rp[node + 1];
  float s0 = 0.f, s1 = 0.f;
  int e = beg;
  if (e + 8 <= end) {
    int i0 = srt[e],     i1 = srt[e + 1], i2 = srt[e + 2], i3 = srt[e + 3];
    int i4 = srt[e + 4], i5 = srt[e + 5], i6 = srt[e + 6], i7 = srt[e + 7];
    while (true) {
      int ne = e + 8;
      bool more = (ne + 8 <= end);
      int j0, j1, j2, j3, j4, j5, j6, j7;
      if (more) {
        j0 = srt[ne];     j1 = srt[ne + 1]; j2 = srt[ne + 2]; j3 = srt[ne + 3];
        j4 = srt[ne + 4]; j5 = srt[ne + 5]; j6 = srt[ne + 6]; j7 = srt[ne + 7];
      }
      float x0 = bf2f(hin[(size_t)i0 * 64 + lane]);
      float x1 = bf2f(hin[(size_t)i1 * 64 + lane]);
      float x2 = bf2f(hin[(size_t)i2 * 64 + lane]);
      float x3 = bf2f(hin[(size_t)i3 * 64 + lane]);
      float x4 = bf2f(hin[(size_t)i4 * 64 + lane]);
      float x5 = bf2f(hin[(size_t)i5 * 64 + lane]);
      float x6 = bf2f(hin[(size_t)i6 * 64 + lane]);
      float x7 = bf2f(hin[(size_t)i7 * 64 + lane]);
      s0 += (x0 + x1) + (x2 + x3);
      s1 += (x4 + x5) + (x6 + x7);
      e = ne;
      if (!more) break;
      i0 = j0; i1 = j1; i2 = j2; i3 = j3; i4 = j4; i5 = j5; i6 = j6; i7 = j7;
    }
  }
  if (e + 4 <= end) {
    int n0 = srt[e], n1 = srt[e + 1], n2 = srt[e + 2], n3 = srt[e + 3];
    float x0 = bf2f(hin[(size_t)n0 * 64 + lane]);
    float x1 = bf2f(hin[(size_t)n1 * 64 + lane]);
    float x2 = bf2f(hin[(size_t)n2 * 64 + lane]);
    float x3 = bf2f(hin[(size_t)n3 * 64 + lane]);
    s0 += (x0 + x1);
    s1 += (x2 + x3);
    e += 4;
  }
  if (e + 2 <= end) {
    int n0 = srt[e], n1 = srt[e + 1];
    s0 += bf2f(hin[(size_t)n0 * 64 + lane]);
    s1 += bf2f(hin[(size_t)n1 * 64 + lane]);
    e += 2;
  }
  if (e < end) s0 += bf2f(hin[(size_t)srt[e] * 64 + lane]);
  float nv = norm[node];
  float h = (s0 + s1) * nv;
  size_t o = (size_t)node * 64 + lane;
  accum[o] += h;
  hout[o] = f2bf(h * nv);
}

// ---------------- weight transpose+cast ----------------
__global__ void k_transW(const float* __restrict__ W, unsigned short* __restrict__ WT, int K) {
  int c = blockIdx.x;
  for (int k = threadIdx.x; k < K; k += blockDim.x)
    WT[(size_t)c * K + k] = f2bf(W[(size_t)k * 256 + c]);
}

// ---------------- MFMA GEMM: pipelined staging + coalesced C-store ----------------
// MODE 0: A = COEF*A0 + ALPHA*A1 (fp32), KTOT=64
// MODE 1: A = relu(af[k]*bf16(A0) + cf[k]), KTOT=256
// part layout: [block][512] = cols 0..255 sum, 256..511 sumsq
template <int KTOT, int MODE>
__global__ __launch_bounds__(256) void k_mfma(
    const void* __restrict__ A0, const float* __restrict__ A1,
    const float* __restrict__ af, const float* __restrict__ cf,
    const unsigned short* __restrict__ BT,
    unsigned short* __restrict__ Yout,
    float* __restrict__ part, int M) {
  constexpr int S = KTOT / 32;
  constexpr int LDA = 40;
  // smemraw overlays: [0,5120) = A buf0, [5120,10240) = A buf1 during K-loop;
  // whole 32KB = C staging tile (64 rows x 128 dwords) in the epilogue.
  __shared__ __align__(16) unsigned char smemraw[32768];
  unsigned short* const Al0 = (unsigned short*)smemraw;
  unsigned short* const Al1 = (unsigned short*)(smemraw + 5120);
  unsigned int* const Cl = (unsigned int*)smemraw;
  __shared__ float afl[256], cfl[256];

  const int tid = threadIdx.x;
  const int wid = tid >> 6, lane = tid & 63;
  const int rbase = blockIdx.x * 64;
  const int nbase = wid * 64;
  const int lr = lane & 15;
  const int kg = lane >> 4;
  const int r = tid >> 2;
  const int c8 = (tid & 3) * 8;
  int arow = rbase + r; if (arow >= M) arow = M - 1;

  if constexpr (MODE == 1) {
    afl[tid] = af[tid];
    cfl[tid] = cf[tid];
    __syncthreads();
  }

  uint4 rw[2]; // transformed+packed A chunk (8 bf16) per pipeline slot

  auto LOADX = [&](int s, int buf) {
    float xv[8];
    if constexpr (MODE == 0) {
      const float* ap = (const float*)A0 + (size_t)arow * 64 + s * 32 + c8;
      const float* fp = A1 + (size_t)arow * 64 + s * 32 + c8;
      float4 a0 = *(const float4*)ap, a1v = *(const float4*)(ap + 4);
      float4 f0 = *(const float4*)fp, f1 = *(const float4*)(fp + 4);
      xv[0] = COEF * a0.x + ALPHA_C * f0.x;  xv[1] = COEF * a0.y + ALPHA_C * f0.y;
      xv[2] = COEF * a0.z + ALPHA_C * f0.z;  xv[3] = COEF * a0.w + ALPHA_C * f0.w;
      xv[4] = COEF * a1v.x + ALPHA_C * f1.x; xv[5] = COEF * a1v.y + ALPHA_C * f1.y;
      xv[6] = COEF * a1v.z + ALPHA_C * f1.z; xv[7] = COEF * a1v.w + ALPHA_C * f1.w;
    } else {
      uint4 v = *(const uint4*)((const unsigned short*)A0 + (size_t)arow * 256 + s * 32 + c8);
      unsigned int u[4] = { v.x, v.y, v.z, v.w };
#pragma unroll
      for (int h = 0; h < 4; h++) {
        int kc = s * 32 + c8 + h * 2;
        xv[h * 2]     = fmaxf(fmaf(afl[kc],     bf2f(u[h] & 0xffffu), cfl[kc]),     0.f);
        xv[h * 2 + 1] = fmaxf(fmaf(afl[kc + 1], bf2f(u[h] >> 16),     cfl[kc + 1]), 0.f);
      }
    }
    uint4 pk;
    pk.x = (unsigned int)f2bf(xv[0]) | ((unsigned int)f2bf(xv[1]) << 16);
    pk.y = (unsigned int)f2bf(xv[2]) | ((unsigned int)f2bf(xv[3]) << 16);
    pk.z = (unsigned int)f2bf(xv[4]) | ((unsigned int)f2bf(xv[5]) << 16);
    pk.w = (unsigned int)f2bf(xv[6]) | ((unsigned int)f2bf(xv[7]) << 16);
    rw[buf] = pk;
  };

  f32x4 acc[4][4];
#pragma unroll
  for (int i = 0; i < 4; i++)
#pragma unroll
    for (int j = 0; j < 4; j++) acc[i][j] = (f32x4){0.f, 0.f, 0.f, 0.f};

  // prologue: fill both pipeline slots, stage chunk 0
  LOADX(0, 0);
  if constexpr (S > 1) LOADX(1, 1);
  *(uint4*)&Al0[r * LDA + c8] = rw[0];

#pragma unroll
  for (int s = 0; s < S; s++) {
    __syncthreads();
    const unsigned short* Alr = (s & 1) ? Al1 : Al0;
    unsigned short* Alw = (s & 1) ? Al0 : Al1;
    // B frags for this step (global, L2-hot) — issue early
    short8 bfrag[4];
#pragma unroll
    for (int ni = 0; ni < 4; ni++)
      bfrag[ni] = *(const short8*)(BT + (size_t)(nbase + ni * 16 + lr) * KTOT + s * 32 + kg * 8);
    // stage next chunk into the other buffer; refill the freed slot
    if (s + 1 < S) *(uint4*)&Alw[r * LDA + c8] = rw[(s + 1) & 1];
    if (s + 2 < S) LOADX(s + 2, s & 1);
    // A frags + MFMA
    short8 afrag[4];
#pragma unroll
    for (int mi = 0; mi < 4; mi++)
      afrag[mi] = *(const short8*)&Alr[(mi * 16 + lr) * LDA + kg * 8];
#pragma unroll
    for (int mi = 0; mi < 4; mi++)
#pragma unroll
      for (int ni = 0; ni < 4; ni++)
        acc[mi][ni] = __builtin_amdgcn_mfma_f32_16x16x32_bf16(afrag[mi], bfrag[ni],
                                                              acc[mi][ni], 0, 0, 0);
  }

  // ---- epilogue: stage C tile in LDS (pair-packed, kg-swizzled), then coalesced store
  __syncthreads(); // all A-buf reads done; smemraw becomes Cl
#pragma unroll
  for (int mi = 0; mi < 4; mi++)
#pragma unroll
    for (int ni = 0; ni < 4; ni++)
#pragma unroll
      for (int reg = 0; reg < 4; reg++) {
        float v = acc[mi][ni][reg];
        float pv = __shfl_xor(v, 1);
        if (!(lr & 1)) {
          int row = mi * 16 + kg * 4 + reg;
          int cd = (nbase >> 1) + ni * 8 + (lr >> 1);
          unsigned int pk = (unsigned int)f2bf(v) | ((unsigned int)f2bf(pv) << 16);
          Cl[row * 128 + (cd ^ (kg << 3))] = pk;
        }
      }

  // BN partials (reg-only + shfl) overlap with LDS staging
  float s4[4] = {0.f, 0.f, 0.f, 0.f};
  float q4[4] = {0.f, 0.f, 0.f, 0.f};
#pragma unroll
  for (int mi = 0; mi < 4; mi++) {
#pragma unroll
    for (int reg = 0; reg < 4; reg++) {
      int row = rbase + mi * 16 + kg * 4 + reg;
      if (row < M) {
#pragma unroll
        for (int ni = 0; ni < 4; ni++) {
          float v = acc[mi][ni][reg];
          s4[ni] += v;
          q4[ni] = fmaf(v, v, q4[ni]);
        }
      }
    }
  }
  float* pb = part + (size_t)blockIdx.x * 512;
#pragma unroll
  for (int ni = 0; ni < 4; ni++) {
    float s = s4[ni], q = q4[ni];
    s += __shfl_xor(s, 16); s += __shfl_xor(s, 32);
    q += __shfl_xor(q, 16); q += __shfl_xor(q, 32);
    if (kg == 0) {
      int col = nbase + ni * 16 + lr;
      pb[col] = s;
      pb[256 + col] = q;
    }
  }

  __syncthreads();
  // coalesced Y store: 8 passes x 256 threads; 32 consecutive threads = one 512B row
#pragma unroll
  for (int p = 0; p < 8; p++) {
    int flat = p * 256 + tid;
    int row = flat >> 5;
    int u4 = flat & 31;
    int m = ((row >> 2) & 3) << 3;
    uint4 vv = *(const uint4*)&Cl[row * 128 + ((u4 * 4) ^ m)];
    int grow = rbase + row;
    if (grow < M)
      *(uint4*)(Yout + (size_t)grow * 256 + u4 * 8) = vv;
  }
}

// ---------------- partial reduction (no atomics) ----------------
__global__ __launch_bounds__(512) void k_red(const float* __restrict__ part,
                                             float* __restrict__ red2) {
  int t = threadIdx.x;
  const int per = (GB1 + NRED - 1) / NRED;
  int b0 = blockIdx.x * per;
  int b1 = b0 + per; if (b1 > GB1) b1 = GB1;
  float s = 0.f;
  for (int b = b0; b < b1; b++) s += part[(size_t)b * 512 + t];
  red2[(size_t)blockIdx.x * 512 + t] = s;
}

__global__ void k_fold(const float* __restrict__ red2,
                       const float* __restrict__ gam, const float* __restrict__ bet,
                       float* __restrict__ af, float* __restrict__ cfv) {
  int c = threadIdx.x;
  float s = 0.f, q = 0.f;
#pragma unroll
  for (int r = 0; r < NRED; r++) {
    s += red2[(size_t)r * 512 + c];
    q += red2[(size_t)r * 512 + 256 + c];
  }
  float m = s * (1.0f / NN);
  float var = q * (1.0f / NN) - m * m;
  float a = gam[c] * rsqrtf(var + EPS_C);
  af[c] = a;
  cfv[c] = bet[c] - m * a;
}

// ---------------- GEMM3 (fp32 vector): [M,256] x [256,40] ----------------
__global__ __launch_bounds__(256) void k_gemm3(
    const unsigned short* __restrict__ Y2, const float* __restrict__ af,
    const float* __restrict__ cfv, const float* __restrict__ W3,
    const float* __restrict__ b3, float* __restrict__ out, int M) {
  __shared__ float Al[256 * 33];
  __shared__ float Wl[256 * 40];
  __shared__ float afl[256], cfl[256];
  int tid = threadIdx.x;
#pragma unroll
  for (int l = 0; l < 40; l++) Wl[l * 256 + tid] = W3[l * 256 + tid];
  afl[tid] = af[tid]; cfl[tid] = cfv[tid];
  __syncthreads();
  int rbase = blockIdx.x * 256;
  int rg = tid >> 3;
  int cg = tid & 7;
  float acc[8][5];
#pragma unroll
  for (int i = 0; i < 8; i++)
#pragma unroll
    for (int j = 0; j < 5; j++) acc[i][j] = 0.f;

  for (int k0 = 0; k0 < 256; k0 += 32) {
    int row = rbase + tid; if (row >= M) row = M - 1;
    const uint4* p = (const uint4*)(Y2 + (size_t)row * 256 + k0);
    uint4 vv[4]; vv[0] = p[0]; vv[1] = p[1]; vv[2] = p[2]; vv[3] = p[3];
    float* ap = &Al[tid * 33];
#pragma unroll
    for (int q = 0; q < 4; q++) {
      unsigned int u[4] = { vv[q].x, vv[q].y, vv[q].z, vv[q].w };
#pragma unroll
      for (int h = 0; h < 4; h++) {
        int kc = k0 + q * 8 + h * 2;
        float x0 = bf2f(u[h] & 0xffffu);
        float x1 = bf2f(u[h] >> 16);
        x0 = fmaxf(fmaf(afl[kc], x0, cfl[kc]), 0.f);
        x1 = fmaxf(fmaf(afl[kc + 1], x1, cfl[kc + 1]), 0.f);
        ap[q * 8 + h * 2] = x0; ap[q * 8 + h * 2 + 1] = x1;
      }
    }
    __syncthreads();
#pragma unroll 4
    for (int kk = 0; kk < 32; kk++) {
      float b[5];
#pragma unroll
      for (int j = 0; j < 5; j++) b[j] = Wl[(k0 + kk) * 40 + cg * 5 + j];
#pragma unroll
      for (int i = 0; i < 8; i++) {
        float a = Al[(rg + 32 * i) * 33 + kk];
#pragma unroll
        for (int j = 0; j < 5; j++) acc[i][j] = fmaf(a, b[j], acc[i][j]);
      }
    }
    __syncthreads();
  }
#pragma unroll
  for (int i = 0; i < 8; i++) {
    int row = rbase + rg + 32 * i;
    if (row < M) {
#pragma unroll
      for (int j = 0; j < 5; j++)
        out[(size_t)row * 40 + cg * 5 + j] = acc[i][j] + b3[cg * 5 + j];
    }
  }
}

// ---------------- launch ----------------

extern "C" void kernel_launch(void* const* d_in, const int* in_sizes, int n_in,
                              void* d_out, int out_size, void* d_ws, size_t ws_size,
                              hipStream_t stream) {
  const float* feat = (const float*)d_in[0];
  const int* src = (const int*)d_in[1];
  const int* dstv = (const int*)d_in[2];
  const float* W1 = (const float*)d_in[3];
  const float* g1 = (const float*)d_in[5];
  const float* be1 = (const float*)d_in[6];
  const float* W2 = (const float*)d_in[7];
  const float* g2 = (const float*)d_in[9];
  const float* be2 = (const float*)d_in[10];
  const float* W3 = (const float*)d_in[11];
  const float* b3 = (const float*)d_in[12];
  float* out = (float*)d_out;

  char* w = (char*)d_ws;
  size_t off = 0;
  auto alloc = [&](size_t bytes) -> char* {
    char* p = w + off;
    off = (off + bytes + 255) & ~(size_t)255;
    return p;
  };
  int* deg = (int*)alloc((size_t)NN * 4);
  int* rp = (int*)alloc((size_t)(NN + 1) * 4);
  int* bsum = (int*)alloc(256);
  int* boff = (int*)alloc(256);
  int* bcur = (int*)alloc((size_t)NBUCK * 4);
  float* norm = (float*)alloc((size_t)NN * 4);
  int* srt = (int*)alloc((size_t)EE * 4);
  unsigned int* pairbuf = (unsigned int*)alloc((size_t)EE * 4);
  unsigned short* hsA = (unsigned short*)alloc((size_t)NN * 64 * 2);
  unsigned short* hsB = (unsigned short*)alloc((size_t)NN * 64 * 2);
  float* accb = (float*)alloc((size_t)NN * 64 * 4);
  unsigned short* Y1 = (unsigned short*)alloc((size_t)NN * 256 * 2);
  unsigned short* Y2 = (unsigned short*)alloc((size_t)NN * 256 * 2);
  unsigned short* W1T = (unsigned short*)alloc(256 * 64 * 2);
  unsigned short* W2T = (unsigned short*)alloc(256 * 256 * 2);
  float* part = (float*)alloc((size_t)GB1 * 512 * 4);
  float* red2 = (float*)alloc((size_t)NRED * 512 * 4);
  float* a1 = (float*)alloc(256 * 4);
  float* c1 = (float*)alloc(256 * 4);
  float* a2 = (float*)alloc(256 * 4);
  float* c2 = (float*)alloc(256 * 4);

  hipMemsetAsync(deg, 0, (size_t)NN * 4, stream);

  const int EB = (EE + 255) / 256;
  const int NB = (NN + 255) / 256;
  const int SB = (NN + 2047) / 2048;
  const int BB = (EE + EPB - 1) / EPB; // 153

  k_count<<<EB, 256, 0, stream>>>(dstv, deg);
  k_transW<<<256, 64, 0, stream>>>(W1, W1T, 64);
  k_transW<<<256, 256, 0, stream>>>(W2, W2T, 256);
  k_scan1<<<SB, 256, 0, stream>>>(deg, rp, bsum);
  k_scan2<<<1, 64, 0, stream>>>(bsum, boff, SB);
  k_scan3<<<NB, 256, 0, stream>>>(rp, boff, deg, norm, bcur);
  k_bucket<<<BB, 256, 0, stream>>>(src, dstv, bcur, pairbuf);
  k_local<<<NBUCK, 256, 0, stream>>>(pairbuf, rp, srt);

  k_init<<<(NN * 16 + 255) / 256, 256, 0, stream>>>((const float4*)feat, norm,
                                                    (uint2*)hsA, (float4*)accb);
  k_gather<<<(NN + 3) / 4, 256, 0, stream>>>(hsA, hsB, accb, rp, srt, norm);
  k_gather<<<(NN + 3) / 4, 256, 0, stream>>>(hsB, hsA, accb, rp, srt, norm);
  k_gather<<<(NN + 3) / 4, 256, 0, stream>>>(hsA, hsB, accb, rp, srt, norm);
  k_gather<<<(NN + 3) / 4, 256, 0, stream>>>(hsB, hsA, accb, rp, srt, norm);

  k_mfma<64, 0><<<GB1, 256, 0, stream>>>(accb, feat, nullptr, nullptr, W1T, Y1, part, NN);
  k_red<<<NRED, 512, 0, stream>>>(part, red2);
  k_fold<<<1, 256, 0, stream>>>(red2, g1, be1, a1, c1);
  k_mfma<256, 1><<<GB1, 256, 0, stream>>>(Y1, nullptr, a1, c1, W2T, Y2, part, NN);
  k_red<<<NRED, 512, 0, stream>>>(part, red2);
  k_fold<<<1, 256, 0, stream>>>(red2, g2, be2, a2, c2);
  k_gemm3<<<NB, 256, 0, stream>>>(Y2, a2, c2, W3, b3, out, NN);
}

// Round 6
// 562.144 us; speedup vs baseline: 1.0739x; 1.0739x over previous
//
#include <hip/hip_runtime.h>

#define NN 100000
#define EE 1250000
#define DD 64
#define HH 256
#define NC_OUT 40
#define ALPHA_C 0.05f
#define COEF 0.2375f /* (1-ALPHA)/K */
#define EPS_C 1e-5f
#define NBUCK 391   /* ceil(NN/256) */
#define EPB 8192    /* edges per bucket-histogram block */
#define NB2 782     /* ceil(NN/128) gemm blocks */
#define PART_ROWS (NB2 * 2)
#define NRED 16

typedef __attribute__((ext_vector_type(8))) short short8;
typedef __attribute__((ext_vector_type(4))) float f32x4;

static __device__ __forceinline__ float bf2f(unsigned int u) {
  union { float f; unsigned int i; } x; x.i = u << 16; return x.f;
}
static __device__ __forceinline__ unsigned short f2bf(float f) {
  unsigned int x = __float_as_uint(f);
  unsigned int r = (x + 0x7FFFu + ((x >> 16) & 1u)) >> 16;
  return (unsigned short)r;
}
static __device__ __forceinline__ float bfat(uint4 v, int j) {
  unsigned int u = ((const unsigned int*)&v)[j >> 1];
  return bf2f((j & 1) ? (u >> 16) : (u & 0xffffu));
}

// ---------------- graph preprocessing ----------------

__global__ void k_count(const int* __restrict__ dst, int* __restrict__ deg) {
  int e = blockIdx.x * 256 + threadIdx.x;
  if (e < EE) atomicAdd(&deg[dst[e]], 1);
}

__global__ void k_scan1(const int* __restrict__ deg, int* __restrict__ rp,
                        int* __restrict__ bsum) {
  __shared__ int ts[256];
  int t = threadIdx.x;
  int base = blockIdx.x * 2048 + t * 8;
  int v[8]; int s = 0;
#pragma unroll
  for (int l = 0; l < 8; l++) { int i = base + l; v[l] = (i < NN) ? deg[i] : 0; s += v[l]; }
  ts[t] = s; __syncthreads();
  for (int off = 1; off < 256; off <<= 1) {
    int x = (t >= off) ? ts[t - off] : 0;
    __syncthreads();
    ts[t] += x;
    __syncthreads();
  }
  int run = ts[t] - s;
#pragma unroll
  for (int l = 0; l < 8; l++) { int i = base + l; if (i < NN) rp[i] = run; run += v[l]; }
  if (t == 255) bsum[blockIdx.x] = ts[255];
}

__global__ void k_scan2(const int* __restrict__ bsum, int* __restrict__ boff, int nb) {
  __shared__ int ts[64];
  int t = threadIdx.x;
  int x = (t < nb) ? bsum[t] : 0;
  ts[t] = x; __syncthreads();
  for (int off = 1; off < 64; off <<= 1) {
    int y = (t >= off) ? ts[t - off] : 0;
    __syncthreads();
    ts[t] += y;
    __syncthreads();
  }
  boff[t] = ts[t] - x;
}

__global__ void k_scan3(int* __restrict__ rp, const int* __restrict__ boff,
                        const int* __restrict__ deg, float* __restrict__ norm,
                        float* __restrict__ rnorm, int* __restrict__ bcur) {
  int i = blockIdx.x * 256 + threadIdx.x;
  if (i < NN) {
    int r = rp[i] + boff[i >> 11];
    rp[i] = r;
    if ((i & 255) == 0) bcur[i >> 8] = r;
    int d = deg[i]; if (d < 1) d = 1;
    norm[i] = rsqrtf((float)d);
    rnorm[i] = sqrtf((float)d);
    if (i == 0) rp[NN] = EE;
  }
}

// pass B: scatter edges into per-bucket regions as packed words (src | local<<24)
__global__ __launch_bounds__(256) void k_bucket(const int* __restrict__ src,
                                                const int* __restrict__ dst,
                                                int* __restrict__ bcur,
                                                unsigned int* __restrict__ pairbuf) {
  __shared__ int hist[NBUCK];
  __shared__ int gbase[NBUCK];
  __shared__ int lcur[NBUCK];
  int tid = threadIdx.x;
  int e0 = blockIdx.x * EPB;
  int e1 = e0 + EPB; if (e1 > EE) e1 = EE;
  for (int i = tid; i < NBUCK; i += 256) { hist[i] = 0; lcur[i] = 0; }
  __syncthreads();
  for (int e = e0 + tid; e < e1; e += 256) {
    int b = dst[e] >> 8;
    atomicAdd(&hist[b], 1);
  }
  __syncthreads();
  for (int b = tid; b < NBUCK; b += 256) {
    int h = hist[b];
    gbase[b] = h ? atomicAdd(&bcur[b], h) : 0;
  }
  __syncthreads();
  for (int e = e0 + tid; e < e1; e += 256) {
    int d = dst[e];
    int b = d >> 8;
    int r = atomicAdd(&lcur[b], 1);
    pairbuf[gbase[b] + r] = (unsigned int)src[e] | ((unsigned int)(d & 255) << 24);
  }
}

// pass C: one block per bucket; LDS cursors scatter into the bucket's srt region
__global__ __launch_bounds__(256) void k_local(const unsigned int* __restrict__ pairbuf,
                                               const int* __restrict__ rp,
                                               int* __restrict__ srt) {
  __shared__ int cur[256];
  int b = blockIdx.x;
  int node0 = b << 8;
  int t = threadIdx.x;
  int node = node0 + t;
  cur[t] = (node < NN) ? rp[node] : 0;
  int lo = rp[node0];
  int hi = (node0 + 256 <= NN) ? rp[node0 + 256] : EE;
  __syncthreads();
  for (int e = lo + t; e < hi; e += 256) {
    unsigned int w = pairbuf[e];
    int s = (int)(w & 0x1FFFFu);
    int l = (int)(w >> 24);
    int p = atomicAdd(&cur[l], 1);
    srt[p] = s;
  }
}

// ---------------- propagation (hs in bf16, no accumulator buffer) ----------------

__global__ void k_init(const float4* __restrict__ feat4, const float* __restrict__ norm,
                       uint2* __restrict__ hs) {
  int i = blockIdx.x * 256 + threadIdx.x;
  if (i < NN * 16) {
    float nv = norm[i >> 4];
    float4 f = feat4[i];
    uint2 o;
    o.x = (unsigned int)f2bf(f.x * nv) | ((unsigned int)f2bf(f.y * nv) << 16);
    o.y = (unsigned int)f2bf(f.z * nv) | ((unsigned int)f2bf(f.w * nv) << 16);
    hs[i] = o;
  }
}

// one wave per node, lane = feature (D=64); hs bf16; writes only hout = h*norm
__global__ void k_gather(const unsigned short* __restrict__ hin,
                         unsigned short* __restrict__ hout,
                         const int* __restrict__ rp,
                         const int* __restrict__ srt, const float* __restrict__ norm) {
  int node = blockIdx.x * 4 + (threadIdx.x >> 6);
  int lane = threadIdx.x & 63;
  if (node >= NN) return;
  int beg = rp[node], end = rp[node + 1];
  float s0 = 0.f, s1 = 0.f;
  int e = beg;
  for (; e + 8 <= end; e += 8) {
    int n0 = srt[e], n1 = srt[e + 1], n2 = srt[e + 2], n3 = srt[e + 3];
    int n4 = srt[e + 4], n5 = srt[e + 5], n6 = srt[e + 6], n7 = srt[e + 7];
    float x0 = bf2f(hin[(size_t)n0 * 64 + lane]);
    float x1 = bf2f(hin[(size_t)n1 * 64 + lane]);
    float x2 = bf2f(hin[(size_t)n2 * 64 + lane]);
    float x3 = bf2f(hin[(size_t)n3 * 64 + lane]);
    float x4 = bf2f(hin[(size_t)n4 * 64 + lane]);
    float x5 = bf2f(hin[(size_t)n5 * 64 + lane]);
    float x6 = bf2f(hin[(size_t)n6 * 64 + lane]);
    float x7 = bf2f(hin[(size_t)n7 * 64 + lane]);
    s0 += (x0 + x1) + (x2 + x3);
    s1 += (x4 + x5) + (x6 + x7);
  }
  if (e + 4 <= end) {
    int n0 = srt[e], n1 = srt[e + 1], n2 = srt[e + 2], n3 = srt[e + 3];
    float x0 = bf2f(hin[(size_t)n0 * 64 + lane]);
    float x1 = bf2f(hin[(size_t)n1 * 64 + lane]);
    float x2 = bf2f(hin[(size_t)n2 * 64 + lane]);
    float x3 = bf2f(hin[(size_t)n3 * 64 + lane]);
    s0 += (x0 + x1);
    s1 += (x2 + x3);
    e += 4;
  }
  if (e + 2 <= end) {
    int n0 = srt[e], n1 = srt[e + 1];
    s0 += bf2f(hin[(size_t)n0 * 64 + lane]);
    s1 += bf2f(hin[(size_t)n1 * 64 + lane]);
    e += 2;
  }
  if (e < end) s0 += bf2f(hin[(size_t)srt[e] * 64 + lane]);
  float nv = norm[node];
  hout[(size_t)node * 64 + lane] = f2bf((s0 + s1) * nv * nv);
}

// ---------------- weight cast to fragment-tiled layout ----------------
// BTt elem index: s*8192 + col*32 + kg*8 + j  == bf16(W[(s*32+kg*8+j)*256 + col])
// so a wave's B-frag load (col = c0..c0+15, kg = 0..3) is 1KB contiguous.
__global__ void k_transWT(const float* __restrict__ W, unsigned short* __restrict__ BTt,
                          int K) {
  int col = blockIdx.x;
  int t = threadIdx.x;           // (s*4+kg) < K/8
  if (t >= (K >> 3)) return;
  int s = t >> 2, kg = t & 3;
  size_t o = (size_t)s * 8192 + (size_t)col * 32 + kg * 8;
#pragma unroll
  for (int j = 0; j < 8; j++)
    BTt[o + j] = f2bf(W[(size_t)(s * 32 + kg * 8 + j) * 256 + col]);
}

// ---------------- MFMA GEMM (BM=128, 8 waves) + per-block BN partials ----------------
// MODE 0: A = COEF*rnorm*(h1+h2+h3+h4) + ALPHA*feat, KTOT=64
// MODE 1: A = relu(af[k]*Yin + cf[k]), KTOT=256
// part rows: [block*2 + rowg][512] = cols 0..255 sum, 256..511 sumsq
template <int KTOT, int MODE>
__global__ __launch_bounds__(512) void k_mfma(
    const unsigned short* __restrict__ h1, const unsigned short* __restrict__ h2,
    const unsigned short* __restrict__ h3, const unsigned short* __restrict__ h4,
    const float* __restrict__ feat, const float* __restrict__ rnorm,
    const unsigned short* __restrict__ Yin,
    const float* __restrict__ af, const float* __restrict__ cf,
    const unsigned short* __restrict__ BTt,
    unsigned short* __restrict__ Yout, float* __restrict__ part, int M) {
  constexpr int S = KTOT / 32;
  constexpr int LDA = 40;
  __shared__ unsigned short Al[128 * LDA];
  __shared__ float afl[256], cfl[256];
  const int tid = threadIdx.x;
  const int wid = tid >> 6, lane = tid & 63;
  const int rowg = wid >> 2, colg = wid & 3;
  const int rbase = blockIdx.x * 128;
  const int lr = lane & 15;
  const int kg = lane >> 4;
  const int r = tid >> 2;
  const int c8 = (tid & 3) * 8;
  int arow = rbase + r; if (arow >= M) arow = M - 1;

  if constexpr (MODE == 1) {
    if (tid < 256) { afl[tid] = af[tid]; cfl[tid] = cf[tid]; }
    __syncthreads();
  }

  f32x4 acc[4][4];
#pragma unroll
  for (int i = 0; i < 4; i++)
#pragma unroll
    for (int j = 0; j < 4; j++) acc[i][j] = (f32x4){0.f, 0.f, 0.f, 0.f};

  for (int s = 0; s < S; s++) {
    // ---- stage A tile [128][32] with fused transform ----
    {
      float xv[8];
      if constexpr (MODE == 0) {
        size_t ho = (size_t)arow * 64 + s * 32 + c8;
        uint4 v1 = *(const uint4*)(h1 + ho);
        uint4 v2 = *(const uint4*)(h2 + ho);
        uint4 v3 = *(const uint4*)(h3 + ho);
        uint4 v4 = *(const uint4*)(h4 + ho);
        float rc = rnorm[arow] * COEF;
        const float* fp = feat + ho;
        float4 f0 = *(const float4*)fp, f1 = *(const float4*)(fp + 4);
        float ff[8] = { f0.x, f0.y, f0.z, f0.w, f1.x, f1.y, f1.z, f1.w };
#pragma unroll
        for (int j = 0; j < 8; j++) {
          float sm = (bfat(v1, j) + bfat(v2, j)) + (bfat(v3, j) + bfat(v4, j));
          xv[j] = rc * sm + ALPHA_C * ff[j];
        }
      } else {
        uint4 v = *(const uint4*)(Yin + (size_t)arow * 256 + s * 32 + c8);
        unsigned int u[4] = { v.x, v.y, v.z, v.w };
#pragma unroll
        for (int h = 0; h < 4; h++) {
          int kc = s * 32 + c8 + h * 2;
          xv[h * 2]     = fmaxf(fmaf(afl[kc],     bf2f(u[h] & 0xffffu), cfl[kc]),     0.f);
          xv[h * 2 + 1] = fmaxf(fmaf(afl[kc + 1], bf2f(u[h] >> 16),     cfl[kc + 1]), 0.f);
        }
      }
      uint4 pk;
      pk.x = (unsigned int)f2bf(xv[0]) | ((unsigned int)f2bf(xv[1]) << 16);
      pk.y = (unsigned int)f2bf(xv[2]) | ((unsigned int)f2bf(xv[3]) << 16);
      pk.z = (unsigned int)f2bf(xv[4]) | ((unsigned int)f2bf(xv[5]) << 16);
      pk.w = (unsigned int)f2bf(xv[6]) | ((unsigned int)f2bf(xv[7]) << 16);
      *(uint4*)&Al[r * LDA + c8] = pk;
    }
    __syncthreads();

    // ---- B frags: fragment-tiled, 1KB contiguous per wave-load ----
    short8 bfrag[4];
#pragma unroll
    for (int ni = 0; ni < 4; ni++) {
      int col = colg * 64 + ni * 16 + lr;
      bfrag[ni] = *(const short8*)(BTt + (size_t)s * 8192 + (size_t)col * 32 + kg * 8);
    }
    short8 afrag[4];
#pragma unroll
    for (int mi = 0; mi < 4; mi++)
      afrag[mi] = *(const short8*)&Al[(rowg * 64 + mi * 16 + lr) * LDA + kg * 8];
#pragma unroll
    for (int mi = 0; mi < 4; mi++)
#pragma unroll
      for (int ni = 0; ni < 4; ni++)
        acc[mi][ni] = __builtin_amdgcn_mfma_f32_16x16x32_bf16(afrag[mi], bfrag[ni],
                                                              acc[mi][ni], 0, 0, 0);
    __syncthreads();
  }

  // ---- C store (bf16): col=lane&15, row=(lane>>4)*4+reg ----
#pragma unroll
  for (int mi = 0; mi < 4; mi++) {
#pragma unroll
    for (int reg = 0; reg < 4; reg++) {
      int row = rbase + rowg * 64 + mi * 16 + kg * 4 + reg;
      if (row < M) {
#pragma unroll
        for (int ni = 0; ni < 4; ni++) {
          int col = colg * 64 + ni * 16 + lr;
          Yout[(size_t)row * 256 + col] = f2bf(acc[mi][ni][reg]);
        }
      }
    }
  }

  // ---- BN partials ----
  float s4[4] = {0.f, 0.f, 0.f, 0.f};
  float q4[4] = {0.f, 0.f, 0.f, 0.f};
#pragma unroll
  for (int mi = 0; mi < 4; mi++) {
#pragma unroll
    for (int reg = 0; reg < 4; reg++) {
      int row = rbase + rowg * 64 + mi * 16 + kg * 4 + reg;
      if (row < M) {
#pragma unroll
        for (int ni = 0; ni < 4; ni++) {
          float v = acc[mi][ni][reg];
          s4[ni] += v;
          q4[ni] = fmaf(v, v, q4[ni]);
        }
      }
    }
  }
  float* pb = part + ((size_t)blockIdx.x * 2 + rowg) * 512;
#pragma unroll
  for (int ni = 0; ni < 4; ni++) {
    float s = s4[ni], q = q4[ni];
    s += __shfl_xor(s, 16); s += __shfl_xor(s, 32);
    q += __shfl_xor(q, 16); q += __shfl_xor(q, 32);
    if (kg == 0) {
      int col = colg * 64 + ni * 16 + lr;
      pb[col] = s;
      pb[256 + col] = q;
    }
  }
}

// ---------------- partial reduction (no atomics) ----------------
__global__ __launch_bounds__(512) void k_red(const float* __restrict__ part,
                                             float* __restrict__ red2) {
  int t = threadIdx.x;
  const int per = (PART_ROWS + NRED - 1) / NRED;
  int b0 = blockIdx.x * per;
  int b1 = b0 + per; if (b1 > PART_ROWS) b1 = PART_ROWS;
  float s = 0.f;
  for (int b = b0; b < b1; b++) s += part[(size_t)b * 512 + t];
  red2[(size_t)blockIdx.x * 512 + t] = s;
}

__global__ void k_fold(const float* __restrict__ red2,
                       const float* __restrict__ gam, const float* __restrict__ bet,
                       float* __restrict__ af, float* __restrict__ cfv) {
  int c = threadIdx.x;
  float s = 0.f, q = 0.f;
#pragma unroll
  for (int r = 0; r < NRED; r++) {
    s += red2[(size_t)r * 512 + c];
    q += red2[(size_t)r * 512 + 256 + c];
  }
  float m = s * (1.0f / NN);
  float var = q * (1.0f / NN) - m * m;
  float a = gam[c] * rsqrtf(var + EPS_C);
  af[c] = a;
  cfv[c] = bet[c] - m * a;
}

// ---------------- GEMM3 (fp32 vector): [M,256] x [256,40] ----------------
__global__ __launch_bounds__(256) void k_gemm3(
    const unsigned short* __restrict__ Y2, const float* __restrict__ af,
    const float* __restrict__ cfv, const float* __restrict__ W3,
    const float* __restrict__ b3, float* __restrict__ out, int M) {
  __shared__ float Al[256 * 33];
  __shared__ float Wl[256 * 40];
  __shared__ float afl[256], cfl[256];
  int tid = threadIdx.x;
#pragma unroll
  for (int l = 0; l < 40; l++) Wl[l * 256 + tid] = W3[l * 256 + tid];
  afl[tid] = af[tid]; cfl[tid] = cfv[tid];
  __syncthreads();
  int rbase = blockIdx.x * 256;
  int rg = tid >> 3;
  int cg = tid & 7;
  float acc[8][5];
#pragma unroll
  for (int i = 0; i < 8; i++)
#pragma unroll
    for (int j = 0; j < 5; j++) acc[i][j] = 0.f;

  for (int k0 = 0; k0 < 256; k0 += 32) {
    int row = rbase + tid; if (row >= M) row = M - 1;
    const uint4* p = (const uint4*)(Y2 + (size_t)row * 256 + k0);
    uint4 vv[4]; vv[0] = p[0]; vv[1] = p[1]; vv[2] = p[2]; vv[3] = p[3];
    float* ap = &Al[tid * 33];
#pragma unroll
    for (int q = 0; q < 4; q++) {
      unsigned int u[4] = { vv[q].x, vv[q].y, vv[q].z, vv[q].w };
#pragma unroll
      for (int h = 0; h < 4; h++) {
        int kc = k0 + q * 8 + h * 2;
        float x0 = bf2f(u[h] & 0xffffu);
        float x1 = bf2f(u[h] >> 16);
        x0 = fmaxf(fmaf(afl[kc], x0, cfl[kc]), 0.f);
        x1 = fmaxf(fmaf(afl[kc + 1], x1, cfl[kc + 1]), 0.f);
        ap[q * 8 + h * 2] = x0; ap[q * 8 + h * 2 + 1] = x1;
      }
    }
    __syncthreads();
#pragma unroll 4
    for (int kk = 0; kk < 32; kk++) {
      float b[5];
#pragma unroll
      for (int j = 0; j < 5; j++) b[j] = Wl[(k0 + kk) * 40 + cg * 5 + j];
#pragma unroll
      for (int i = 0; i < 8; i++) {
        float a = Al[(rg + 32 * i) * 33 + kk];
#pragma unroll
        for (int j = 0; j < 5; j++) acc[i][j] = fmaf(a, b[j], acc[i][j]);
      }
    }
    __syncthreads();
  }
#pragma unroll
  for (int i = 0; i < 8; i++) {
    int row = rbase + rg + 32 * i;
    if (row < M) {
#pragma unroll
      for (int j = 0; j < 5; j++)
        out[(size_t)row * 40 + cg * 5 + j] = acc[i][j] + b3[cg * 5 + j];
    }
  }
}

// ---------------- launch ----------------

extern "C" void kernel_launch(void* const* d_in, const int* in_sizes, int n_in,
                              void* d_out, int out_size, void* d_ws, size_t ws_size,
                              hipStream_t stream) {
  const float* feat = (const float*)d_in[0];
  const int* src = (const int*)d_in[1];
  const int* dstv = (const int*)d_in[2];
  const float* W1 = (const float*)d_in[3];
  const float* g1 = (const float*)d_in[5];
  const float* be1 = (const float*)d_in[6];
  const float* W2 = (const float*)d_in[7];
  const float* g2 = (const float*)d_in[9];
  const float* be2 = (const float*)d_in[10];
  const float* W3 = (const float*)d_in[11];
  const float* b3 = (const float*)d_in[12];
  float* out = (float*)d_out;

  char* w = (char*)d_ws;
  size_t off = 0;
  auto alloc = [&](size_t bytes) -> char* {
    char* p = w + off;
    off = (off + bytes + 255) & ~(size_t)255;
    return p;
  };
  int* deg = (int*)alloc((size_t)NN * 4);
  int* rp = (int*)alloc((size_t)(NN + 1) * 4);
  int* bsum = (int*)alloc(256);
  int* boff = (int*)alloc(256);
  int* bcur = (int*)alloc((size_t)NBUCK * 4);
  float* norm = (float*)alloc((size_t)NN * 4);
  float* rnorm = (float*)alloc((size_t)NN * 4);
  int* srt = (int*)alloc((size_t)EE * 4);
  unsigned int* pairbuf = (unsigned int*)alloc((size_t)EE * 4);
  unsigned short* hs0 = (unsigned short*)alloc((size_t)NN * 64 * 2);
  unsigned short* hn1 = (unsigned short*)alloc((size_t)NN * 64 * 2);
  unsigned short* hn2 = (unsigned short*)alloc((size_t)NN * 64 * 2);
  unsigned short* hn3 = (unsigned short*)alloc((size_t)NN * 64 * 2);
  unsigned short* hn4 = (unsigned short*)alloc((size_t)NN * 64 * 2);
  unsigned short* Y1 = (unsigned short*)alloc((size_t)NN * 256 * 2);
  unsigned short* Y2 = (unsigned short*)alloc((size_t)NN * 256 * 2);
  unsigned short* W1T = (unsigned short*)alloc(256 * 64 * 2);
  unsigned short* W2T = (unsigned short*)alloc(256 * 256 * 2);
  float* part = (float*)alloc((size_t)PART_ROWS * 512 * 4);
  float* red2 = (float*)alloc((size_t)NRED * 512 * 4);
  float* a1 = (float*)alloc(256 * 4);
  float* c1 = (float*)alloc(256 * 4);
  float* a2 = (float*)alloc(256 * 4);
  float* c2 = (float*)alloc(256 * 4);

  hipMemsetAsync(deg, 0, (size_t)NN * 4, stream);

  const int EB = (EE + 255) / 256;
  const int NB = (NN + 255) / 256;
  const int SB = (NN + 2047) / 2048;
  const int BB = (EE + EPB - 1) / EPB; // 153

  k_count<<<EB, 256, 0, stream>>>(dstv, deg);
  k_transWT<<<256, 64, 0, stream>>>(W1, W1T, 64);
  k_transWT<<<256, 64, 0, stream>>>(W2, W2T, 256);
  k_scan1<<<SB, 256, 0, stream>>>(deg, rp, bsum);
  k_scan2<<<1, 64, 0, stream>>>(bsum, boff, SB);
  k_scan3<<<NB, 256, 0, stream>>>(rp, boff, deg, norm, rnorm, bcur);
  k_bucket<<<BB, 256, 0, stream>>>(src, dstv, bcur, pairbuf);
  k_local<<<NBUCK, 256, 0, stream>>>(pairbuf, rp, srt);

  k_init<<<(NN * 16 + 255) / 256, 256, 0, stream>>>((const float4*)feat, norm, (uint2*)hs0);
  k_gather<<<(NN + 3) / 4, 256, 0, stream>>>(hs0, hn1, rp, srt, norm);
  k_gather<<<(NN + 3) / 4, 256, 0, stream>>>(hn1, hn2, rp, srt, norm);
  k_gather<<<(NN + 3) / 4, 256, 0, stream>>>(hn2, hn3, rp, srt, norm);
  k_gather<<<(NN + 3) / 4, 256, 0, stream>>>(hn3, hn4, rp, srt, norm);

  k_mfma<64, 0><<<NB2, 512, 0, stream>>>(hn1, hn2, hn3, hn4, feat, rnorm,
                                         nullptr, nullptr, nullptr, W1T, Y1, part, NN);
  k_red<<<NRED, 512, 0, stream>>>(part, red2);
  k_fold<<<1, 256, 0, stream>>>(red2, g1, be1, a1, c1);
  k_mfma<256, 1><<<NB2, 512, 0, stream>>>(nullptr, nullptr, nullptr, nullptr, nullptr,
                                          nullptr, Y1, a1, c1, W2T, Y2, part, NN);
  k_red<<<NRED, 512, 0, stream>>>(part, red2);
  k_fold<<<1, 256, 0, stream>>>(red2, g2, be2, a2, c2);
  k_gemm3<<<NB, 256, 0, stream>>>(Y2, a2, c2, W3, b3, out, NN);
}

// Round 7
// 545.405 us; speedup vs baseline: 1.1069x; 1.0307x over previous
//
#include <hip/hip_runtime.h>

#define NN 100000
#define EE 1250000
#define DD 64
#define HH 256
#define NC_OUT 40
#define ALPHA_C 0.05f
#define COEF 0.2375f /* (1-ALPHA)/K */
#define EPS_C 1e-5f
#define NBUCK 391   /* ceil(NN/256) */
#define EPB 8192    /* edges per bucket-histogram block */
#define NB2 782     /* ceil(NN/128) gemm blocks */
#define PART_ROWS (NB2 * 2)
#define NRED 16

typedef __attribute__((ext_vector_type(8))) short short8;
typedef __attribute__((ext_vector_type(4))) float f32x4;

static __device__ __forceinline__ float bf2f(unsigned int u) {
  union { float f; unsigned int i; } x; x.i = u << 16; return x.f;
}
static __device__ __forceinline__ unsigned short f2bf(float f) {
  unsigned int x = __float_as_uint(f);
  unsigned int r = (x + 0x7FFFu + ((x >> 16) & 1u)) >> 16;
  return (unsigned short)r;
}
static __device__ __forceinline__ float bfat(uint4 v, int j) {
  unsigned int u = ((const unsigned int*)&v)[j >> 1];
  return bf2f((j & 1) ? (u >> 16) : (u & 0xffffu));
}

// ---------------- graph preprocessing ----------------

__global__ void k_count(const int* __restrict__ dst, int* __restrict__ deg) {
  int e = blockIdx.x * 256 + threadIdx.x;
  if (e < EE) atomicAdd(&deg[dst[e]], 1);
}

__global__ void k_scan1(const int* __restrict__ deg, int* __restrict__ rp,
                        int* __restrict__ bsum) {
  __shared__ int ts[256];
  int t = threadIdx.x;
  int base = blockIdx.x * 2048 + t * 8;
  int v[8]; int s = 0;
#pragma unroll
  for (int l = 0; l < 8; l++) { int i = base + l; v[l] = (i < NN) ? deg[i] : 0; s += v[l]; }
  ts[t] = s; __syncthreads();
  for (int off = 1; off < 256; off <<= 1) {
    int x = (t >= off) ? ts[t - off] : 0;
    __syncthreads();
    ts[t] += x;
    __syncthreads();
  }
  int run = ts[t] - s;
#pragma unroll
  for (int l = 0; l < 8; l++) { int i = base + l; if (i < NN) rp[i] = run; run += v[l]; }
  if (t == 255) bsum[blockIdx.x] = ts[255];
}

__global__ void k_scan2(const int* __restrict__ bsum, int* __restrict__ boff, int nb) {
  __shared__ int ts[64];
  int t = threadIdx.x;
  int x = (t < nb) ? bsum[t] : 0;
  ts[t] = x; __syncthreads();
  for (int off = 1; off < 64; off <<= 1) {
    int y = (t >= off) ? ts[t - off] : 0;
    __syncthreads();
    ts[t] += y;
    __syncthreads();
  }
  boff[t] = ts[t] - x;
}

__global__ void k_scan3(int* __restrict__ rp, const int* __restrict__ boff,
                        const int* __restrict__ deg, float* __restrict__ norm,
                        float* __restrict__ rnorm, int* __restrict__ bcur) {
  int i = blockIdx.x * 256 + threadIdx.x;
  if (i < NN) {
    int r = rp[i] + boff[i >> 11];
    rp[i] = r;
    if ((i & 255) == 0) bcur[i >> 8] = r;
    int d = deg[i]; if (d < 1) d = 1;
    norm[i] = rsqrtf((float)d);
    rnorm[i] = sqrtf((float)d);
    if (i == 0) rp[NN] = EE;
  }
}

// pass B: scatter edges into per-bucket regions as packed words (src | local<<24)
__global__ __launch_bounds__(256) void k_bucket(const int* __restrict__ src,
                                                const int* __restrict__ dst,
                                                int* __restrict__ bcur,
                                                unsigned int* __restrict__ pairbuf) {
  __shared__ int hist[NBUCK];
  __shared__ int gbase[NBUCK];
  __shared__ int lcur[NBUCK];
  int tid = threadIdx.x;
  int e0 = blockIdx.x * EPB;
  int e1 = e0 + EPB; if (e1 > EE) e1 = EE;
  for (int i = tid; i < NBUCK; i += 256) { hist[i] = 0; lcur[i] = 0; }
  __syncthreads();
  for (int e = e0 + tid; e < e1; e += 256) {
    int b = dst[e] >> 8;
    atomicAdd(&hist[b], 1);
  }
  __syncthreads();
  for (int b = tid; b < NBUCK; b += 256) {
    int h = hist[b];
    gbase[b] = h ? atomicAdd(&bcur[b], h) : 0;
  }
  __syncthreads();
  for (int e = e0 + tid; e < e1; e += 256) {
    int d = dst[e];
    int b = d >> 8;
    int r = atomicAdd(&lcur[b], 1);
    pairbuf[gbase[b] + r] = (unsigned int)src[e] | ((unsigned int)(d & 255) << 24);
  }
}

// pass C: one block per bucket; LDS cursors scatter into the bucket's srt region
__global__ __launch_bounds__(256) void k_local(const unsigned int* __restrict__ pairbuf,
                                               const int* __restrict__ rp,
                                               int* __restrict__ srt) {
  __shared__ int cur[256];
  int b = blockIdx.x;
  int node0 = b << 8;
  int t = threadIdx.x;
  int node = node0 + t;
  cur[t] = (node < NN) ? rp[node] : 0;
  int lo = rp[node0];
  int hi = (node0 + 256 <= NN) ? rp[node0 + 256] : EE;
  __syncthreads();
  for (int e = lo + t; e < hi; e += 256) {
    unsigned int w = pairbuf[e];
    int s = (int)(w & 0x1FFFFu);
    int l = (int)(w >> 24);
    int p = atomicAdd(&cur[l], 1);
    srt[p] = s;
  }
}

// ---------------- propagation (hs in bf16) ----------------

__global__ void k_init(const float4* __restrict__ feat4, const float* __restrict__ norm,
                       uint2* __restrict__ hs) {
  int i = blockIdx.x * 256 + threadIdx.x;
  if (i < NN * 16) {
    float nv = norm[i >> 4];
    float4 f = feat4[i];
    uint2 o;
    o.x = (unsigned int)f2bf(f.x * nv) | ((unsigned int)f2bf(f.y * nv) << 16);
    o.y = (unsigned int)f2bf(f.z * nv) | ((unsigned int)f2bf(f.w * nv) << 16);
    hs[i] = o;
  }
}

// quad-packed gather: one wave per node; slot g=lane>>4 picks 1-of-4 neighbors,
// q=lane&15 picks 4 features (uint2). One wave-load covers 4 neighbor rows.
__global__ void k_gather(const unsigned int* __restrict__ hin,
                         unsigned int* __restrict__ hout,
                         const int* __restrict__ rp,
                         const int* __restrict__ srt, const float* __restrict__ norm) {
  int node = blockIdx.x * 4 + (threadIdx.x >> 6);
  int lane = threadIdx.x & 63;
  if (node >= NN) return;
  int beg = rp[node], end = rp[node + 1];
  int g = lane >> 4;
  int q = lane & 15;
  float f0 = 0.f, f1 = 0.f, f2 = 0.f, f3 = 0.f;
  int e = beg;
  for (; e + 8 <= end; e += 8) {
    int nA = srt[e + g];
    int nB = srt[e + 4 + g];
    uint2 uA = *(const uint2*)&hin[(size_t)nA * 32 + q * 2];
    uint2 uB = *(const uint2*)&hin[(size_t)nB * 32 + q * 2];
    f0 += bf2f(uA.x & 0xffffu) + bf2f(uB.x & 0xffffu);
    f1 += bf2f(uA.x >> 16)     + bf2f(uB.x >> 16);
    f2 += bf2f(uA.y & 0xffffu) + bf2f(uB.y & 0xffffu);
    f3 += bf2f(uA.y >> 16)     + bf2f(uB.y >> 16);
  }
  if (e + 4 <= end) {
    int nA = srt[e + g];
    uint2 uA = *(const uint2*)&hin[(size_t)nA * 32 + q * 2];
    f0 += bf2f(uA.x & 0xffffu);
    f1 += bf2f(uA.x >> 16);
    f2 += bf2f(uA.y & 0xffffu);
    f3 += bf2f(uA.y >> 16);
    e += 4;
  }
  int rem = end - e; // 0..3
  if (g < rem) {
    int nA = srt[e + g];
    uint2 uA = *(const uint2*)&hin[(size_t)nA * 32 + q * 2];
    f0 += bf2f(uA.x & 0xffffu);
    f1 += bf2f(uA.x >> 16);
    f2 += bf2f(uA.y & 0xffffu);
    f3 += bf2f(uA.y >> 16);
  }
  f0 += __shfl_xor(f0, 16); f0 += __shfl_xor(f0, 32);
  f1 += __shfl_xor(f1, 16); f1 += __shfl_xor(f1, 32);
  f2 += __shfl_xor(f2, 16); f2 += __shfl_xor(f2, 32);
  f3 += __shfl_xor(f3, 16); f3 += __shfl_xor(f3, 32);
  if (lane < 16) {
    float nv = norm[node];
    float nv2 = nv * nv;
    uint2 o;
    o.x = (unsigned int)f2bf(f0 * nv2) | ((unsigned int)f2bf(f1 * nv2) << 16);
    o.y = (unsigned int)f2bf(f2 * nv2) | ((unsigned int)f2bf(f3 * nv2) << 16);
    *(uint2*)&hout[(size_t)node * 32 + q * 2] = o;
  }
}

// ---------------- weight cast to fragment-tiled layout ----------------
// BTt elem: s*8192 + col*32 + kg*8 + j == bf16(W[(s*32+kg*8+j)*256 + col]) (N=256)
__global__ void k_transWT(const float* __restrict__ W, unsigned short* __restrict__ BTt,
                          int K) {
  int col = blockIdx.x;
  int t = threadIdx.x;
  if (t >= (K >> 3)) return;
  int s = t >> 2, kg = t & 3;
  size_t o = (size_t)s * 8192 + (size_t)col * 32 + kg * 8;
#pragma unroll
  for (int j = 0; j < 8; j++)
    BTt[o + j] = f2bf(W[(size_t)(s * 32 + kg * 8 + j) * 256 + col]);
}

// W3 [256][40] -> fragment-tiled [8][48][32], cols >= 40 zero
__global__ void k_transW3(const float* __restrict__ W3, unsigned short* __restrict__ BT3) {
  int col = blockIdx.x;  // 0..47
  int t = threadIdx.x;   // 0..31
  int s = t >> 2, kg = t & 3;
  size_t o = (size_t)s * 1536 + (size_t)col * 32 + kg * 8;
#pragma unroll
  for (int j = 0; j < 8; j++)
    BT3[o + j] = (col < NC_OUT) ? f2bf(W3[(size_t)(s * 32 + kg * 8 + j) * NC_OUT + col]) : 0;
}

// ---------------- MFMA GEMM (BM=128, 8 waves) + per-block BN partials ----------------
// MODE 0: A = COEF*rnorm*(h1+h2+h3+h4) + ALPHA*feat, KTOT=64
// MODE 1: A = relu(af[k]*Yin + cf[k]), KTOT=256
template <int KTOT, int MODE>
__global__ __launch_bounds__(512) void k_mfma(
    const unsigned short* __restrict__ h1, const unsigned short* __restrict__ h2,
    const unsigned short* __restrict__ h3, const unsigned short* __restrict__ h4,
    const float* __restrict__ feat, const float* __restrict__ rnorm,
    const unsigned short* __restrict__ Yin,
    const float* __restrict__ af, const float* __restrict__ cf,
    const unsigned short* __restrict__ BTt,
    unsigned short* __restrict__ Yout, float* __restrict__ part, int M) {
  constexpr int S = KTOT / 32;
  constexpr int LDA = 40;
  __shared__ unsigned short Al[128 * LDA];
  __shared__ float afl[256], cfl[256];
  const int tid = threadIdx.x;
  const int wid = tid >> 6, lane = tid & 63;
  const int rowg = wid >> 2, colg = wid & 3;
  const int rbase = blockIdx.x * 128;
  const int lr = lane & 15;
  const int kg = lane >> 4;
  const int r = tid >> 2;
  const int c8 = (tid & 3) * 8;
  int arow = rbase + r; if (arow >= M) arow = M - 1;

  if constexpr (MODE == 1) {
    if (tid < 256) { afl[tid] = af[tid]; cfl[tid] = cf[tid]; }
    __syncthreads();
  }

  f32x4 acc[4][4];
#pragma unroll
  for (int i = 0; i < 4; i++)
#pragma unroll
    for (int j = 0; j < 4; j++) acc[i][j] = (f32x4){0.f, 0.f, 0.f, 0.f};

  for (int s = 0; s < S; s++) {
    {
      float xv[8];
      if constexpr (MODE == 0) {
        size_t ho = (size_t)arow * 64 + s * 32 + c8;
        uint4 v1 = *(const uint4*)(h1 + ho);
        uint4 v2 = *(const uint4*)(h2 + ho);
        uint4 v3 = *(const uint4*)(h3 + ho);
        uint4 v4 = *(const uint4*)(h4 + ho);
        float rc = rnorm[arow] * COEF;
        const float* fp = feat + ho;
        float4 f0 = *(const float4*)fp, f1v = *(const float4*)(fp + 4);
        float ff[8] = { f0.x, f0.y, f0.z, f0.w, f1v.x, f1v.y, f1v.z, f1v.w };
#pragma unroll
        for (int j = 0; j < 8; j++) {
          float sm = (bfat(v1, j) + bfat(v2, j)) + (bfat(v3, j) + bfat(v4, j));
          xv[j] = rc * sm + ALPHA_C * ff[j];
        }
      } else {
        uint4 v = *(const uint4*)(Yin + (size_t)arow * 256 + s * 32 + c8);
        unsigned int u[4] = { v.x, v.y, v.z, v.w };
#pragma unroll
        for (int h = 0; h < 4; h++) {
          int kc = s * 32 + c8 + h * 2;
          xv[h * 2]     = fmaxf(fmaf(afl[kc],     bf2f(u[h] & 0xffffu), cfl[kc]),     0.f);
          xv[h * 2 + 1] = fmaxf(fmaf(afl[kc + 1], bf2f(u[h] >> 16),     cfl[kc + 1]), 0.f);
        }
      }
      uint4 pk;
      pk.x = (unsigned int)f2bf(xv[0]) | ((unsigned int)f2bf(xv[1]) << 16);
      pk.y = (unsigned int)f2bf(xv[2]) | ((unsigned int)f2bf(xv[3]) << 16);
      pk.z = (unsigned int)f2bf(xv[4]) | ((unsigned int)f2bf(xv[5]) << 16);
      pk.w = (unsigned int)f2bf(xv[6]) | ((unsigned int)f2bf(xv[7]) << 16);
      *(uint4*)&Al[r * LDA + c8] = pk;
    }
    __syncthreads();

    short8 bfrag[4];
#pragma unroll
    for (int ni = 0; ni < 4; ni++) {
      int col = colg * 64 + ni * 16 + lr;
      bfrag[ni] = *(const short8*)(BTt + (size_t)s * 8192 + (size_t)col * 32 + kg * 8);
    }
    short8 afrag[4];
#pragma unroll
    for (int mi = 0; mi < 4; mi++)
      afrag[mi] = *(const short8*)&Al[(rowg * 64 + mi * 16 + lr) * LDA + kg * 8];
#pragma unroll
    for (int mi = 0; mi < 4; mi++)
#pragma unroll
      for (int ni = 0; ni < 4; ni++)
        acc[mi][ni] = __builtin_amdgcn_mfma_f32_16x16x32_bf16(afrag[mi], bfrag[ni],
                                                              acc[mi][ni], 0, 0, 0);
    __syncthreads();
  }

#pragma unroll
  for (int mi = 0; mi < 4; mi++) {
#pragma unroll
    for (int reg = 0; reg < 4; reg++) {
      int row = rbase + rowg * 64 + mi * 16 + kg * 4 + reg;
      if (row < M) {
#pragma unroll
        for (int ni = 0; ni < 4; ni++) {
          int col = colg * 64 + ni * 16 + lr;
          Yout[(size_t)row * 256 + col] = f2bf(acc[mi][ni][reg]);
        }
      }
    }
  }

  float s4[4] = {0.f, 0.f, 0.f, 0.f};
  float q4[4] = {0.f, 0.f, 0.f, 0.f};
#pragma unroll
  for (int mi = 0; mi < 4; mi++) {
#pragma unroll
    for (int reg = 0; reg < 4; reg++) {
      int row = rbase + rowg * 64 + mi * 16 + kg * 4 + reg;
      if (row < M) {
#pragma unroll
        for (int ni = 0; ni < 4; ni++) {
          float v = acc[mi][ni][reg];
          s4[ni] += v;
          q4[ni] = fmaf(v, v, q4[ni]);
        }
      }
    }
  }
  float* pb = part + ((size_t)blockIdx.x * 2 + rowg) * 512;
#pragma unroll
  for (int ni = 0; ni < 4; ni++) {
    float s = s4[ni], q = q4[ni];
    s += __shfl_xor(s, 16); s += __shfl_xor(s, 32);
    q += __shfl_xor(q, 16); q += __shfl_xor(q, 32);
    if (kg == 0) {
      int col = colg * 64 + ni * 16 + lr;
      pb[col] = s;
      pb[256 + col] = q;
    }
  }
}

// ---------------- MFMA GEMM3: [M,256] x [256,48pad] -> fp32 out[M,40] ----------------
__global__ __launch_bounds__(512) void k_mfma3(
    const unsigned short* __restrict__ Yin,
    const float* __restrict__ af, const float* __restrict__ cf,
    const unsigned short* __restrict__ BT3, const float* __restrict__ b3,
    float* __restrict__ out, int M) {
  constexpr int LDA = 40;
  __shared__ unsigned short Al[128 * LDA];
  __shared__ float afl[256], cfl[256], b3l[48];
  const int tid = threadIdx.x;
  const int wid = tid >> 6, lane = tid & 63;
  const int rbase = blockIdx.x * 128;
  const int lr = lane & 15;
  const int kg = lane >> 4;
  const int r = tid >> 2;
  const int c8 = (tid & 3) * 8;
  int arow = rbase + r; if (arow >= M) arow = M - 1;

  if (tid < 256) { afl[tid] = af[tid]; cfl[tid] = cf[tid]; }
  if (tid >= 256 && tid < 304) b3l[tid - 256] = (tid - 256 < NC_OUT) ? b3[tid - 256] : 0.f;
  __syncthreads();

  f32x4 acc[3];
#pragma unroll
  for (int j = 0; j < 3; j++) acc[j] = (f32x4){0.f, 0.f, 0.f, 0.f};

  for (int s = 0; s < 8; s++) {
    {
      uint4 v = *(const uint4*)(Yin + (size_t)arow * 256 + s * 32 + c8);
      unsigned int u[4] = { v.x, v.y, v.z, v.w };
      float xv[8];
#pragma unroll
      for (int h = 0; h < 4; h++) {
        int kc = s * 32 + c8 + h * 2;
        xv[h * 2]     = fmaxf(fmaf(afl[kc],     bf2f(u[h] & 0xffffu), cfl[kc]),     0.f);
        xv[h * 2 + 1] = fmaxf(fmaf(afl[kc + 1], bf2f(u[h] >> 16),     cfl[kc + 1]), 0.f);
      }
      uint4 pk;
      pk.x = (unsigned int)f2bf(xv[0]) | ((unsigned int)f2bf(xv[1]) << 16);
      pk.y = (unsigned int)f2bf(xv[2]) | ((unsigned int)f2bf(xv[3]) << 16);
      pk.z = (unsigned int)f2bf(xv[4]) | ((unsigned int)f2bf(xv[5]) << 16);
      pk.w = (unsigned int)f2bf(xv[6]) | ((unsigned int)f2bf(xv[7]) << 16);
      *(uint4*)&Al[r * LDA + c8] = pk;
    }
    __syncthreads();

    short8 bfrag[3];
#pragma unroll
    for (int ni = 0; ni < 3; ni++) {
      int col = ni * 16 + lr;
      bfrag[ni] = *(const short8*)(BT3 + (size_t)s * 1536 + (size_t)col * 32 + kg * 8);
    }
    short8 afrag = *(const short8*)&Al[(wid * 16 + lr) * LDA + kg * 8];
#pragma unroll
    for (int ni = 0; ni < 3; ni++)
      acc[ni] = __builtin_amdgcn_mfma_f32_16x16x32_bf16(afrag, bfrag[ni], acc[ni], 0, 0, 0);
    __syncthreads();
  }

#pragma unroll
  for (int reg = 0; reg < 4; reg++) {
    int row = rbase + wid * 16 + kg * 4 + reg;
    if (row < M) {
#pragma unroll
      for (int ni = 0; ni < 3; ni++) {
        int col = ni * 16 + lr;
        if (col < NC_OUT)
          out[(size_t)row * NC_OUT + col] = acc[ni][reg] + b3l[col];
      }
    }
  }
}

// ---------------- partial reduction (no atomics) ----------------
__global__ __launch_bounds__(512) void k_red(const float* __restrict__ part,
                                             float* __restrict__ red2) {
  int t = threadIdx.x;
  const int per = (PART_ROWS + NRED - 1) / NRED;
  int b0 = blockIdx.x * per;
  int b1 = b0 + per; if (b1 > PART_ROWS) b1 = PART_ROWS;
  float s = 0.f;
  for (int b = b0; b < b1; b++) s += part[(size_t)b * 512 + t];
  red2[(size_t)blockIdx.x * 512 + t] = s;
}

__global__ void k_fold(const float* __restrict__ red2,
                       const float* __restrict__ gam, const float* __restrict__ bet,
                       float* __restrict__ af, float* __restrict__ cfv) {
  int c = threadIdx.x;
  float s = 0.f, q = 0.f;
#pragma unroll
  for (int r = 0; r < NRED; r++) {
    s += red2[(size_t)r * 512 + c];
    q += red2[(size_t)r * 512 + 256 + c];
  }
  float m = s * (1.0f / NN);
  float var = q * (1.0f / NN) - m * m;
  float a = gam[c] * rsqrtf(var + EPS_C);
  af[c] = a;
  cfv[c] = bet[c] - m * a;
}

// ---------------- launch ----------------

extern "C" void kernel_launch(void* const* d_in, const int* in_sizes, int n_in,
                              void* d_out, int out_size, void* d_ws, size_t ws_size,
                              hipStream_t stream) {
  const float* feat = (const float*)d_in[0];
  const int* src = (const int*)d_in[1];
  const int* dstv = (const int*)d_in[2];
  const float* W1 = (const float*)d_in[3];
  const float* g1 = (const float*)d_in[5];
  const float* be1 = (const float*)d_in[6];
  const float* W2 = (const float*)d_in[7];
  const float* g2 = (const float*)d_in[9];
  const float* be2 = (const float*)d_in[10];
  const float* W3 = (const float*)d_in[11];
  const float* b3 = (const float*)d_in[12];
  float* out = (float*)d_out;

  char* w = (char*)d_ws;
  size_t off = 0;
  auto alloc = [&](size_t bytes) -> char* {
    char* p = w + off;
    off = (off + bytes + 255) & ~(size_t)255;
    return p;
  };
  int* deg = (int*)alloc((size_t)NN * 4);
  int* rp = (int*)alloc((size_t)(NN + 1) * 4);
  int* bsum = (int*)alloc(256);
  int* boff = (int*)alloc(256);
  int* bcur = (int*)alloc((size_t)NBUCK * 4);
  float* norm = (float*)alloc((size_t)NN * 4);
  float* rnorm = (float*)alloc((size_t)NN * 4);
  int* srt = (int*)alloc((size_t)EE * 4);
  unsigned int* pairbuf = (unsigned int*)alloc((size_t)EE * 4);
  unsigned short* hs0 = (unsigned short*)alloc((size_t)NN * 64 * 2);
  unsigned short* hn1 = (unsigned short*)alloc((size_t)NN * 64 * 2);
  unsigned short* hn2 = (unsigned short*)alloc((size_t)NN * 64 * 2);
  unsigned short* hn3 = (unsigned short*)alloc((size_t)NN * 64 * 2);
  unsigned short* hn4 = (unsigned short*)alloc((size_t)NN * 64 * 2);
  unsigned short* Y1 = (unsigned short*)alloc((size_t)NN * 256 * 2);
  unsigned short* Y2 = (unsigned short*)alloc((size_t)NN * 256 * 2);
  unsigned short* W1T = (unsigned short*)alloc(256 * 64 * 2);
  unsigned short* W2T = (unsigned short*)alloc(256 * 256 * 2);
  unsigned short* W3T = (unsigned short*)alloc(48 * 256 * 2);
  float* part = (float*)alloc((size_t)PART_ROWS * 512 * 4);
  float* red2 = (float*)alloc((size_t)NRED * 512 * 4);
  float* a1 = (float*)alloc(256 * 4);
  float* c1 = (float*)alloc(256 * 4);
  float* a2 = (float*)alloc(256 * 4);
  float* c2 = (float*)alloc(256 * 4);

  hipMemsetAsync(deg, 0, (size_t)NN * 4, stream);

  const int EB = (EE + 255) / 256;
  const int NB = (NN + 255) / 256;
  const int SB = (NN + 2047) / 2048;
  const int BB = (EE + EPB - 1) / EPB; // 153

  k_count<<<EB, 256, 0, stream>>>(dstv, deg);
  k_transWT<<<256, 64, 0, stream>>>(W1, W1T, 64);
  k_transWT<<<256, 64, 0, stream>>>(W2, W2T, 256);
  k_transW3<<<48, 32, 0, stream>>>(W3, W3T);
  k_scan1<<<SB, 256, 0, stream>>>(deg, rp, bsum);
  k_scan2<<<1, 64, 0, stream>>>(bsum, boff, SB);
  k_scan3<<<NB, 256, 0, stream>>>(rp, boff, deg, norm, rnorm, bcur);
  k_bucket<<<BB, 256, 0, stream>>>(src, dstv, bcur, pairbuf);
  k_local<<<NBUCK, 256, 0, stream>>>(pairbuf, rp, srt);

  k_init<<<(NN * 16 + 255) / 256, 256, 0, stream>>>((const float4*)feat, norm, (uint2*)hs0);
  k_gather<<<(NN + 3) / 4, 256, 0, stream>>>((const unsigned int*)hs0, (unsigned int*)hn1,
                                             rp, srt, norm);
  k_gather<<<(NN + 3) / 4, 256, 0, stream>>>((const unsigned int*)hn1, (unsigned int*)hn2,
                                             rp, srt, norm);
  k_gather<<<(NN + 3) / 4, 256, 0, stream>>>((const unsigned int*)hn2, (unsigned int*)hn3,
                                             rp, srt, norm);
  k_gather<<<(NN + 3) / 4, 256, 0, stream>>>((const unsigned int*)hn3, (unsigned int*)hn4,
                                             rp, srt, norm);

  k_mfma<64, 0><<<NB2, 512, 0, stream>>>(hn1, hn2, hn3, hn4, feat, rnorm,
                                         nullptr, nullptr, nullptr, W1T, Y1, part, NN);
  k_red<<<NRED, 512, 0, stream>>>(part, red2);
  k_fold<<<1, 256, 0, stream>>>(red2, g1, be1, a1, c1);
  k_mfma<256, 1><<<NB2, 512, 0, stream>>>(nullptr, nullptr, nullptr, nullptr, nullptr,
                                          nullptr, Y1, a1, c1, W2T, Y2, part, NN);
  k_red<<<NRED, 512, 0, stream>>>(part, red2);
  k_fold<<<1, 256, 0, stream>>>(red2, g2, be2, a2, c2);
  k_mfma3<<<NB2, 512, 0, stream>>>(Y2, a2, c2, W3T, b3, out, NN);
}